// Round 7
// baseline (278.892 us; speedup 1.0000x reference)
//
#include <hip/hip_runtime.h>

typedef unsigned short ushort_t;
typedef unsigned int uint_t;
typedef __attribute__((ext_vector_type(8))) short short8;
typedef __attribute__((ext_vector_type(4))) float floatx4;

#define S_LEN 2048
#define D_DIM 1024
#define H_NUM 16
#define HD 64
#define ABUF (128 * 32)
#define BBUF (64 * 32)

__device__ __forceinline__ float bf2f(ushort_t u) {
    union { uint_t i; float f; } c; c.i = ((uint_t)u) << 16; return c.f;
}
__device__ __forceinline__ ushort_t f2bf(float f) {
    union { float f; uint_t i; } c; c.f = f;
    uint_t r = c.i + 0x7fffu + ((c.i >> 16) & 1u);
    return (ushort_t)(r >> 16);
}

// async global->LDS, 16B per lane. LDS dest must be wave-uniform base + lane*16.
__device__ __forceinline__ void g2l16(const ushort_t* g, ushort_t* l) {
    __builtin_amdgcn_global_load_lds(
        (const __attribute__((address_space(1))) void*)g,
        (__attribute__((address_space(3))) void*)l, 16, 0, 0);
}

// ---------------------------------------------------------------- cast x
__global__ __launch_bounds__(256, 4) void cast_x_kernel(
        const float* __restrict__ in, ushort_t* __restrict__ out) {
    const int idx = (blockIdx.x * 256 + threadIdx.x) * 4;
    const float4 v = *(const float4*)(in + idx);
    ushort4 o;
    o.x = f2bf(v.x); o.y = f2bf(v.y); o.z = f2bf(v.z); o.w = f2bf(v.w);
    *(ushort4*)(out + idx) = o;
}

// ---------------------------------------------------------------- transpose+cast (validated R3)
__global__ __launch_bounds__(256, 2) void transpose4_kernel(
        const float* __restrict__ W0, const float* __restrict__ W1,
        const float* __restrict__ W2, const float* __restrict__ W3,
        ushort_t* __restrict__ T0, ushort_t* __restrict__ T1,
        ushort_t* __restrict__ T2, ushort_t* __restrict__ T3) {
    const int z = blockIdx.z;
    const float* in  = (z == 0) ? W0 : (z == 1) ? W1 : (z == 2) ? W2 : W3;
    ushort_t*    out = (z == 0) ? T0 : (z == 1) ? T1 : (z == 2) ? T2 : T3;
    __shared__ __align__(16) ushort_t t[64][65];
    const int r0 = blockIdx.y * 64, c0 = blockIdx.x * 64;
    const int tr = threadIdx.x >> 4;
    const int tc = (threadIdx.x & 15) * 4;
#pragma unroll
    for (int i = 0; i < 4; ++i) {
        const int row = tr + i * 16;
        const float4 v = *(const float4*)(in + (size_t)(r0 + row) * D_DIM + c0 + tc);
        t[row][tc + 0] = f2bf(v.x); t[row][tc + 1] = f2bf(v.y);
        t[row][tc + 2] = f2bf(v.z); t[row][tc + 3] = f2bf(v.w);
    }
    __syncthreads();
#pragma unroll
    for (int i = 0; i < 4; ++i) {
        const int n = tr + i * 16;
        ushort4 v;
        v.x = t[tc + 0][n]; v.y = t[tc + 1][n];
        v.z = t[tc + 2][n]; v.w = t[tc + 3][n];
        *(ushort4*)(out + (size_t)(c0 + n) * D_DIM + r0 + tc) = v;
    }
}

// ---------------------------------------------------------------- MFMA GEMM tile
// R7: 128x64 tile (acc 4x2/wave), BK=32, 4 waves 2x2 of 64x32.
// Rationale: R5/R6 showed GEMMs parallelism-starved (gemm_out = 1 block/CU;
// launch_bounds(256,2) capped residency). Smaller tile -> grids 1536/512,
// launch_bounds(256,4) -> 4 blocks/CU = 16 waves/CU; TLP hides staging
// latency. Double-buffered global_load_lds staging kept (3 loads/thread).
__device__ __forceinline__ void gemm_tile(
        const ushort_t* __restrict__ A, const ushort_t* __restrict__ BT,
        const int m0, const int n0,
        ushort_t* As, ushort_t* Bs, floatx4 acc[4][2]) {
    const int tid  = threadIdx.x;
    const int w    = tid >> 6;
    const int wm   = (w >> 1) * 64;
    const int wn   = (w & 1) * 32;
    const int lrow = tid & 15;
    const int kq   = ((tid & 63) >> 4) * 8;

    const int flat0 = tid * 8;                 // A rows 0..63
    const int flat1 = (256 + tid) * 8;         // A rows 64..127
    const int rowA0 = flat0 >> 5, kkA0 = flat0 & 31;
    const int rowA1 = flat1 >> 5, kkA1 = flat1 & 31;
    const int rowB  = tid >> 2,  kkB  = (tid & 3) * 8;   // B rows 0..63

    const ushort_t* ga0 = A  + (size_t)(m0 + rowA0) * D_DIM + kkA0;
    const ushort_t* ga1 = A  + (size_t)(m0 + rowA1) * D_DIM + kkA1;
    const ushort_t* gb  = BT + (size_t)(n0 + rowB)  * D_DIM + kkB;

    // prologue: stage K-step 0 into buffer 0
    g2l16(ga0, As + flat0);
    g2l16(ga1, As + flat1);
    g2l16(gb,  Bs + tid * 8);
    asm volatile("s_waitcnt vmcnt(0)" ::: "memory");
    __syncthreads();

    int cur = 0;
    for (int k0 = 0; k0 < D_DIM; k0 += 32) {
        const ushort_t* Ac = As + cur * ABUF;
        const ushort_t* Bc = Bs + cur * BBUF;
        short8 av[4], bv[2];
#pragma unroll
        for (int i = 0; i < 4; ++i)
            av[i] = *(const short8*)(Ac + (wm + i * 16 + lrow) * 32 + kq);
#pragma unroll
        for (int j = 0; j < 2; ++j)
            bv[j] = *(const short8*)(Bc + (wn + j * 16 + lrow) * 32 + kq);

        if (k0 + 32 < D_DIM) {          // prefetch next K-step into other buffer
            ushort_t* An = As + (cur ^ 1) * ABUF;
            ushort_t* Bn = Bs + (cur ^ 1) * BBUF;
            g2l16(ga0 + k0 + 32, An + flat0);
            g2l16(ga1 + k0 + 32, An + flat1);
            g2l16(gb  + k0 + 32, Bn + tid * 8);
        }

#pragma unroll
        for (int i = 0; i < 4; ++i)
#pragma unroll
            for (int j = 0; j < 2; ++j)
                acc[i][j] = __builtin_amdgcn_mfma_f32_16x16x32_bf16(
                    av[i], bv[j], acc[i][j], 0, 0, 0);

        asm volatile("s_waitcnt vmcnt(0)" ::: "memory");  // next-step loads landed
        __syncthreads();                                  // all frag reads done
        cur ^= 1;
    }
}

// QKV: z picks weight/dest; writes merged row-major [B*S, D] bf16.
// Q pre-scaled by 0.125*log2(e) so attention softmax runs in exp2 domain.
__global__ __launch_bounds__(256, 4) void gemm_qkv_kernel(
        const ushort_t* __restrict__ A,
        const ushort_t* __restrict__ WqT, const ushort_t* __restrict__ WkT,
        const ushort_t* __restrict__ WvT,
        ushort_t* __restrict__ Qo, ushort_t* __restrict__ Ko,
        ushort_t* __restrict__ Vo) {
    const ushort_t* BT = (blockIdx.z == 0) ? WqT : (blockIdx.z == 1) ? WkT : WvT;
    ushort_t* C        = (blockIdx.z == 0) ? Qo  : (blockIdx.z == 1) ? Ko  : Vo;
    const float sc     = (blockIdx.z == 0) ? 0.18033688f : 1.0f;  // 0.125*log2(e)
    __shared__ __align__(16) ushort_t As[2 * ABUF];
    __shared__ __align__(16) ushort_t Bs[2 * BBUF];
    const int m0 = blockIdx.y * 128, n0 = blockIdx.x * 64;

    floatx4 acc[4][2] = {};
    gemm_tile(A, BT, m0, n0, As, Bs, acc);

    const int tid = threadIdx.x;
    const int w = tid >> 6, wm = (w >> 1) * 64, wn = (w & 1) * 32;
    const int lrow = tid & 15;
    const int rquad = ((tid & 63) >> 4) * 4;
#pragma unroll
    for (int i = 0; i < 4; ++i) {
        const int mbase = m0 + wm + i * 16 + rquad;
#pragma unroll
        for (int j = 0; j < 2; ++j) {
            const int gn = n0 + wn + j * 16 + lrow;
#pragma unroll
            for (int r = 0; r < 4; ++r)
                C[(size_t)(mbase + r) * D_DIM + gn] = f2bf(acc[i][j][r] * sc);
        }
    }
}

// Output projection: f32 out = A @ Wo + bo.
__global__ __launch_bounds__(256, 4) void gemm_out_kernel(
        const ushort_t* __restrict__ A, const ushort_t* __restrict__ WoT,
        const float* __restrict__ bias, float* __restrict__ C) {
    __shared__ __align__(16) ushort_t As[2 * ABUF];
    __shared__ __align__(16) ushort_t Bs[2 * BBUF];
    const int m0 = blockIdx.y * 128, n0 = blockIdx.x * 64;

    floatx4 acc[4][2] = {};
    gemm_tile(A, WoT, m0, n0, As, Bs, acc);

    const int tid = threadIdx.x;
    const int w = tid >> 6, wm = (w >> 1) * 64, wn = (w & 1) * 32;
    const int lrow = tid & 15;
    const int rquad = ((tid & 63) >> 4) * 4;
#pragma unroll
    for (int i = 0; i < 4; ++i) {
        const int mbase = m0 + wm + i * 16 + rquad;
#pragma unroll
        for (int j = 0; j < 2; ++j) {
            const int gn = n0 + wn + j * 16 + lrow;
            const float badd = bias[gn];
#pragma unroll
            for (int r = 0; r < 4; ++r)
                C[(size_t)(mbase + r) * D_DIM + gn] = acc[i][j][r] + badd;
        }
    }
}

// ---------------------------------------------------------------- MFMA flash attention
// R7: softmax in exp2 domain (log2(e) folded into Q pre-scale) -> raw
// v_exp_f32, no per-exp mul; T13 defer-max (THR=11.5 in log2 domain,
// wave-uniform __any branch) skips the O-rescale pass on most tiles.
// T14 register prefetch of next K/V tile (R6-validated). Static (bh,y)
// grid: XCD = bh%8 L2 affinity; CU-balanced qt map {g,15-g,16+g,31-g}.
// Conflict-free swizzled LDS. l-sum reduction deferred to epilogue.
__global__ __launch_bounds__(256, 4) void attn_mfma_kernel(
        const ushort_t* __restrict__ Q, const ushort_t* __restrict__ K,
        const ushort_t* __restrict__ V, ushort_t* __restrict__ O) {
    __shared__ __align__(16) ushort_t Ks[64 * 64];      // [key][d] swizzled
    __shared__ __align__(16) ushort_t Vt[64 * 64];      // [d][key] swizzled
    __shared__ __align__(16) ushort_t Ps[4][16 * 64];   // per-wave P [row][key] swizzled

    const int bh  = blockIdx.x;
    const int b   = bh >> 4, h = bh & 15;
    const int g   = blockIdx.y & 7;            // CU-balanced qt map
    const int p   = blockIdx.y >> 3;
    const int qt  = (p == 0) ? g : (p == 1) ? (15 - g)
                  : (p == 2) ? (16 + g) : (31 - g);
    const int q0  = qt * 64;
    const int tid = threadIdx.x;
    const int wq  = tid >> 6;
    const int lane = tid & 63;
    const int col  = lane & 15;
    const int quad = lane >> 4;
    const int c7 = col & 7;
    const int qw0  = q0 + wq * 16;             // wave's first q-row
    const size_t rowbase = (size_t)b * S_LEN;
    const int ch0 = h * HD;

    // K staging: thread = (key, 32B d-chunk)
    const int skey = tid >> 2;           // 0..63
    const int schk = tid & 3;            // 0..3
    // V staging: thread = (key-pair, 8-wide d-chunk)
    const int vkp = tid & 31;            // key-pair 0..31
    const int vdc = tid >> 5;            // d-chunk 0..7

    // Q A-fragments: lane holds A[m=col][k=quad*8+e]
    short8 aq[2];
#pragma unroll
    for (int kc = 0; kc < 2; ++kc)
        aq[kc] = *(const short8*)(Q + (rowbase + qw0 + col) * D_DIM
                                    + ch0 + kc * 32 + quad * 8);

    floatx4 oacc[4] = {};
    float mrun[4], lrun[4];
#pragma unroll
    for (int r = 0; r < 4; ++r) { mrun[r] = -1e30f; lrun[r] = 0.0f; }

    const int ntiles = qt + 1;

    // ---- prologue: load tile 0 into registers
    short8 krA, krB, vrA, vrB;
    {
        const ushort_t* kg = K + (rowbase + skey) * D_DIM + ch0 + schk * 16;
        krA = *(const short8*)(kg);
        krB = *(const short8*)(kg + 8);
        const ushort_t* vg = V + (rowbase + 2 * vkp) * D_DIM + ch0 + vdc * 8;
        vrA = *(const short8*)(vg);
        vrB = *(const short8*)(vg + D_DIM);
    }

    for (int t = 0; t < ntiles; ++t) {
        const int kb = t * 64;
        __syncthreads();   // previous tile's LDS reads complete
        // ---- write staged registers to LDS (K swizzled, V transposed pair-packed)
        {
            const int sw = skey & 7;
            *(short8*)(Ks + skey * 64 + (((2 * schk) ^ sw) << 3)) = krA;
            *(short8*)(Ks + skey * 64 + (((2 * schk + 1) ^ sw) << 3)) = krB;
        }
#pragma unroll
        for (int e = 0; e < 8; ++e) {
            const int d = vdc * 8 + e;
            const uint_t pk = (uint_t)(ushort_t)vrA[e] | ((uint_t)(ushort_t)vrB[e] << 16);
            *(uint_t*)(Vt + d * 64 + ((2 * vkp) ^ ((d & 7) << 3))) = pk;
        }
        // ---- prefetch next tile into registers (overlaps with compute below)
        {
            const int kbn = (t + 1 < ntiles) ? (t + 1) * 64 : 0;   // clamp: valid addr
            const ushort_t* kg = K + (rowbase + kbn + skey) * D_DIM + ch0 + schk * 16;
            krA = *(const short8*)(kg);
            krB = *(const short8*)(kg + 8);
            const ushort_t* vg = V + (rowbase + kbn + 2 * vkp) * D_DIM + ch0 + vdc * 8;
            vrA = *(const short8*)(vg);
            vrB = *(const short8*)(vg + D_DIM);
        }
        __syncthreads();   // LDS tile ready

        if (kb <= qw0 + 15) {        // wave-uniform: tile has valid keys
            // ---- S = Q K^T (one ds_read_b128 per fragment, conflict-free)
            floatx4 sa[4] = {};
            __builtin_amdgcn_s_setprio(1);
#pragma unroll
            for (int kc = 0; kc < 2; ++kc)
#pragma unroll
                for (int j = 0; j < 4; ++j) {
                    const short8 bk = *(const short8*)(
                        Ks + (j * 16 + col) * 64 + (((kc * 4 + quad) ^ c7) << 3));
                    sa[j] = __builtin_amdgcn_mfma_f32_16x16x32_bf16(
                        aq[kc], bk, sa[j], 0, 0, 0);
                }
            __builtin_amdgcn_s_setprio(0);

            const bool needmask = (kb + 63 > qw0);
            // ---- causal mask (scale pre-folded into Q)
            if (needmask) {
#pragma unroll
                for (int j = 0; j < 4; ++j)
#pragma unroll
                    for (int r = 0; r < 4; ++r) {
                        const int row = qw0 + quad * 4 + r;
                        const int key = kb + j * 16 + col;
                        if (key > row) sa[j][r] = -1e30f;
                    }
            }
            // ---- online softmax, exp2 domain; T13 defer-max
            float mx4[4];
#pragma unroll
            for (int r = 0; r < 4; ++r) {
                float mx = fmaxf(fmaxf(sa[0][r], sa[1][r]),
                                 fmaxf(sa[2][r], sa[3][r]));
                mx = fmaxf(mx, __shfl_xor(mx, 1));
                mx = fmaxf(mx, __shfl_xor(mx, 2));
                mx = fmaxf(mx, __shfl_xor(mx, 4));
                mx = fmaxf(mx, __shfl_xor(mx, 8));
                mx4[r] = mx;
            }
            bool grow = false;
#pragma unroll
            for (int r = 0; r < 4; ++r) grow |= (mx4[r] > mrun[r] + 11.5f);
            if (__any(grow)) {
#pragma unroll
                for (int r = 0; r < 4; ++r) {
                    const float mn = fmaxf(mrun[r], mx4[r]);
                    const float al = __builtin_amdgcn_exp2f(mrun[r] - mn);
                    mrun[r] = mn;
                    float rs = 0.0f;
#pragma unroll
                    for (int j = 0; j < 4; ++j) {
                        const float p2 = __builtin_amdgcn_exp2f(sa[j][r] - mn);
                        sa[j][r] = p2;
                        rs += p2;
                    }
                    lrun[r] = lrun[r] * al + rs;
#pragma unroll
                    for (int jd = 0; jd < 4; ++jd) oacc[jd][r] *= al;
                }
            } else {                 // max stable: no rescale pass
#pragma unroll
                for (int r = 0; r < 4; ++r) {
                    float rs = 0.0f;
#pragma unroll
                    for (int j = 0; j < 4; ++j) {
                        const float p2 = __builtin_amdgcn_exp2f(sa[j][r] - mrun[r]);
                        sa[j][r] = p2;
                        rs += p2;
                    }
                    lrun[r] += rs;
                }
            }
            // ---- write P (bf16) to this wave's swizzled LDS region
            {
                ushort_t* pw = Ps[wq];
#pragma unroll
                for (int j = 0; j < 4; ++j)
#pragma unroll
                    for (int r = 0; r < 4; ++r) {
                        const int row = quad * 4 + r;
                        pw[row * 64 + ((j * 16 + col) ^ ((row & 7) << 3))] =
                            f2bf(sa[j][r]);
                    }
            }
            asm volatile("s_waitcnt lgkmcnt(0)" ::: "memory");   // wave-local RAW
            // ---- O += P V
            __builtin_amdgcn_s_setprio(1);
#pragma unroll
            for (int kc = 0; kc < 2; ++kc) {
                const short8 ap = *(const short8*)(
                    Ps[wq] + col * 64 + (((kc * 4 + quad) ^ c7) << 3));
#pragma unroll
                for (int jd = 0; jd < 4; ++jd) {
                    const short8 bv = *(const short8*)(
                        Vt + (jd * 16 + col) * 64 + (((kc * 4 + quad) ^ c7) << 3));
                    oacc[jd] = __builtin_amdgcn_mfma_f32_16x16x32_bf16(
                        ap, bv, oacc[jd], 0, 0, 0);
                }
            }
            __builtin_amdgcn_s_setprio(0);
        }
    }

    // ---- epilogue: reduce l across the 16 key-lanes, write O bf16
#pragma unroll
    for (int r = 0; r < 4; ++r) {
        float l = lrun[r];
        l += __shfl_xor(l, 1);
        l += __shfl_xor(l, 2);
        l += __shfl_xor(l, 4);
        l += __shfl_xor(l, 8);
        const int row = qw0 + quad * 4 + r;
        const float inv = 1.0f / l;
#pragma unroll
        for (int jd = 0; jd < 4; ++jd)
            O[(rowbase + row) * D_DIM + ch0 + jd * 16 + col] =
                f2bf(oacc[jd][r] * inv);
    }
}

// ---------------------------------------------------------------- launch
extern "C" void kernel_launch(void* const* d_in, const int* in_sizes, int n_in,
                              void* d_out, int out_size, void* d_ws, size_t ws_size,
                              hipStream_t stream) {
    const float* x  = (const float*)d_in[0];
    const float* Wq = (const float*)d_in[1];
    const float* Wk = (const float*)d_in[2];
    const float* Wv = (const float*)d_in[3];
    const float* Wo = (const float*)d_in[4];
    const float* bo = (const float*)d_in[5];
    float* out = (float*)d_out;                // f32 output

    char* ws = (char*)d_ws;
    const size_t MB = 1024 * 1024;
    ushort_t* xb  = (ushort_t*)(ws + 0 * MB);   // 8 MB
    ushort_t* WqT = (ushort_t*)(ws + 8 * MB);   // 2 MB each
    ushort_t* WkT = (ushort_t*)(ws + 10 * MB);
    ushort_t* WvT = (ushort_t*)(ws + 12 * MB);
    ushort_t* WoT = (ushort_t*)(ws + 14 * MB);
    ushort_t* Qb  = (ushort_t*)(ws + 16 * MB);  // [B*S, D] bf16, 8 MB each
    ushort_t* Kb  = (ushort_t*)(ws + 24 * MB);
    ushort_t* Vb  = (ushort_t*)(ws + 32 * MB);
    ushort_t* Ob  = (ushort_t*)(ws + 40 * MB);  // total 48 MB

    cast_x_kernel<<<4096, 256, 0, stream>>>(x, xb);
    transpose4_kernel<<<dim3(16, 16, 4), 256, 0, stream>>>(
        Wq, Wk, Wv, Wo, WqT, WkT, WvT, WoT);

    gemm_qkv_kernel<<<dim3(16, 32, 3), 256, 0, stream>>>(
        xb, WqT, WkT, WvT, Qb, Kb, Vb);

    attn_mfma_kernel<<<dim3(32, 32), 256, 0, stream>>>(Qb, Kb, Vb, Ob);

    gemm_out_kernel<<<dim3(16, 32), 256, 0, stream>>>(Ob, WoT, bo, out);
}

// Round 8
// 198.660 us; speedup vs baseline: 1.4039x; 1.4039x over previous
//
#include <hip/hip_runtime.h>

typedef unsigned short ushort_t;
typedef unsigned int uint_t;
typedef __attribute__((ext_vector_type(8))) short short8;
typedef __attribute__((ext_vector_type(4))) float floatx4;

#define S_LEN 2048
#define D_DIM 1024
#define H_NUM 16
#define HD 64
#define GBUF (128 * 32)

__device__ __forceinline__ float bf2f(ushort_t u) {
    union { uint_t i; float f; } c; c.i = ((uint_t)u) << 16; return c.f;
}
__device__ __forceinline__ ushort_t f2bf(float f) {
    union { float f; uint_t i; } c; c.f = f;
    uint_t r = c.i + 0x7fffu + ((c.i >> 16) & 1u);
    return (ushort_t)(r >> 16);
}

// async global->LDS, 16B per lane. LDS dest must be wave-uniform base + lane*16.
__device__ __forceinline__ void g2l16(const ushort_t* g, ushort_t* l) {
    __builtin_amdgcn_global_load_lds(
        (const __attribute__((address_space(1))) void*)g,
        (__attribute__((address_space(3))) void*)l, 16, 0, 0);
}

// ---------------------------------------------------------------- cast x
__global__ __launch_bounds__(256, 4) void cast_x_kernel(
        const float* __restrict__ in, ushort_t* __restrict__ out) {
    const int idx = (blockIdx.x * 256 + threadIdx.x) * 4;
    const float4 v = *(const float4*)(in + idx);
    ushort4 o;
    o.x = f2bf(v.x); o.y = f2bf(v.y); o.z = f2bf(v.z); o.w = f2bf(v.w);
    *(ushort4*)(out + idx) = o;
}

// ---------------------------------------------------------------- transpose+cast (validated R3)
__global__ __launch_bounds__(256, 2) void transpose4_kernel(
        const float* __restrict__ W0, const float* __restrict__ W1,
        const float* __restrict__ W2, const float* __restrict__ W3,
        ushort_t* __restrict__ T0, ushort_t* __restrict__ T1,
        ushort_t* __restrict__ T2, ushort_t* __restrict__ T3) {
    const int z = blockIdx.z;
    const float* in  = (z == 0) ? W0 : (z == 1) ? W1 : (z == 2) ? W2 : W3;
    ushort_t*    out = (z == 0) ? T0 : (z == 1) ? T1 : (z == 2) ? T2 : T3;
    __shared__ __align__(16) ushort_t t[64][65];
    const int r0 = blockIdx.y * 64, c0 = blockIdx.x * 64;
    const int tr = threadIdx.x >> 4;
    const int tc = (threadIdx.x & 15) * 4;
#pragma unroll
    for (int i = 0; i < 4; ++i) {
        const int row = tr + i * 16;
        const float4 v = *(const float4*)(in + (size_t)(r0 + row) * D_DIM + c0 + tc);
        t[row][tc + 0] = f2bf(v.x); t[row][tc + 1] = f2bf(v.y);
        t[row][tc + 2] = f2bf(v.z); t[row][tc + 3] = f2bf(v.w);
    }
    __syncthreads();
#pragma unroll
    for (int i = 0; i < 4; ++i) {
        const int n = tr + i * 16;
        ushort4 v;
        v.x = t[tc + 0][n]; v.y = t[tc + 1][n];
        v.z = t[tc + 2][n]; v.w = t[tc + 3][n];
        *(ushort4*)(out + (size_t)(c0 + n) * D_DIM + r0 + tc) = v;
    }
}

// ---------------------------------------------------------------- MFMA GEMM tile
// C[M,N] = A[M,K] @ B with BT = B^T [N,K] row-major. 128x128 tile, BK=32,
// 4 waves 2x2 of 64x64, 16x16x32 bf16 MFMA. (R6-validated structure.)
// 2-phase double-buffered global_load_lds staging: ds_read frags from buf
// cur -> issue loads for k0+32 into buf cur^1 -> MFMA -> vmcnt(0)+barrier.
__device__ __forceinline__ void gemm_tile(
        const ushort_t* __restrict__ A, const ushort_t* __restrict__ BT,
        const int m0, const int n0,
        ushort_t* As, ushort_t* Bs, floatx4 acc[4][4]) {
    const int tid  = threadIdx.x;
    const int w    = tid >> 6;
    const int wm   = (w >> 1) * 64;
    const int wn   = (w & 1) * 64;
    const int lrow = tid & 15;
    const int kq   = ((tid & 63) >> 4) * 8;

    const int flat0 = tid * 8;
    const int flat1 = (256 + tid) * 8;
    const int row0 = flat0 >> 5, kk0 = flat0 & 31;
    const int row1 = flat1 >> 5, kk1 = flat1 & 31;

    const ushort_t* ga0 = A  + (size_t)(m0 + row0) * D_DIM + kk0;
    const ushort_t* gb0 = BT + (size_t)(n0 + row0) * D_DIM + kk0;
    const ushort_t* ga1 = A  + (size_t)(m0 + row1) * D_DIM + kk1;
    const ushort_t* gb1 = BT + (size_t)(n0 + row1) * D_DIM + kk1;

    // prologue: stage K-step 0 into buffer 0
    g2l16(ga0, As + flat0);
    g2l16(gb0, Bs + flat0);
    g2l16(ga1, As + flat1);
    g2l16(gb1, Bs + flat1);
    asm volatile("s_waitcnt vmcnt(0)" ::: "memory");
    __syncthreads();

    int cur = 0;
    for (int k0 = 0; k0 < D_DIM; k0 += 32) {
        const ushort_t* Ac = As + cur * GBUF;
        const ushort_t* Bc = Bs + cur * GBUF;
        short8 av[4], bv[4];
#pragma unroll
        for (int i = 0; i < 4; ++i)
            av[i] = *(const short8*)(Ac + (wm + i * 16 + lrow) * 32 + kq);
#pragma unroll
        for (int j = 0; j < 4; ++j)
            bv[j] = *(const short8*)(Bc + (wn + j * 16 + lrow) * 32 + kq);

        if (k0 + 32 < D_DIM) {          // prefetch next K-step into other buffer
            ushort_t* An = As + (cur ^ 1) * GBUF;
            ushort_t* Bn = Bs + (cur ^ 1) * GBUF;
            g2l16(ga0 + k0 + 32, An + flat0);
            g2l16(gb0 + k0 + 32, Bn + flat0);
            g2l16(ga1 + k0 + 32, An + flat1);
            g2l16(gb1 + k0 + 32, Bn + flat1);
        }

#pragma unroll
        for (int i = 0; i < 4; ++i)
#pragma unroll
            for (int j = 0; j < 4; ++j)
                acc[i][j] = __builtin_amdgcn_mfma_f32_16x16x32_bf16(
                    av[i], bv[j], acc[i][j], 0, 0, 0);

        asm volatile("s_waitcnt vmcnt(0)" ::: "memory");  // next-step loads landed
        __syncthreads();                                  // all frag reads done
        cur ^= 1;
    }
}

// QKV: z picks weight/dest; writes merged row-major [B*S, D] bf16.
// Q pre-scaled by 0.125*log2(e): attention softmax runs in exp2 domain.
// R8: launch_bounds(256,3) -- grid supplies 3 blocks/CU (768/256); R6's
// (256,2) cap forced 1.5 serialized residency rounds. VGPR cap @3 is ~168,
// kernel needs ~120 -> no spill risk.
__global__ __launch_bounds__(256, 3) void gemm_qkv_kernel(
        const ushort_t* __restrict__ A,
        const ushort_t* __restrict__ WqT, const ushort_t* __restrict__ WkT,
        const ushort_t* __restrict__ WvT,
        ushort_t* __restrict__ Qo, ushort_t* __restrict__ Ko,
        ushort_t* __restrict__ Vo) {
    const ushort_t* BT = (blockIdx.z == 0) ? WqT : (blockIdx.z == 1) ? WkT : WvT;
    ushort_t* C        = (blockIdx.z == 0) ? Qo  : (blockIdx.z == 1) ? Ko  : Vo;
    const float sc     = (blockIdx.z == 0) ? 0.18033688f : 1.0f;  // 0.125*log2(e)
    __shared__ __align__(16) ushort_t As[2 * GBUF];
    __shared__ __align__(16) ushort_t Bs[2 * GBUF];
    const int m0 = blockIdx.y * 128, n0 = blockIdx.x * 128;

    floatx4 acc[4][4] = {};
    gemm_tile(A, BT, m0, n0, As, Bs, acc);

    const int tid = threadIdx.x;
    const int w = tid >> 6, wm = (w >> 1) * 64, wn = (w & 1) * 64;
    const int lrow = tid & 15;
    const int rquad = ((tid & 63) >> 4) * 4;
#pragma unroll
    for (int i = 0; i < 4; ++i) {
        const int mbase = m0 + wm + i * 16 + rquad;
#pragma unroll
        for (int j = 0; j < 4; ++j) {
            const int gn = n0 + wn + j * 16 + lrow;
#pragma unroll
            for (int r = 0; r < 4; ++r)
                C[(size_t)(mbase + r) * D_DIM + gn] = f2bf(acc[i][j][r] * sc);
        }
    }
}

// Output projection: f32 out = A @ Wo + bo.
__global__ __launch_bounds__(256, 2) void gemm_out_kernel(
        const ushort_t* __restrict__ A, const ushort_t* __restrict__ WoT,
        const float* __restrict__ bias, float* __restrict__ C) {
    __shared__ __align__(16) ushort_t As[2 * GBUF];
    __shared__ __align__(16) ushort_t Bs[2 * GBUF];
    const int m0 = blockIdx.y * 128, n0 = blockIdx.x * 128;

    floatx4 acc[4][4] = {};
    gemm_tile(A, WoT, m0, n0, As, Bs, acc);

    const int tid = threadIdx.x;
    const int w = tid >> 6, wm = (w >> 1) * 64, wn = (w & 1) * 64;
    const int lrow = tid & 15;
    const int rquad = ((tid & 63) >> 4) * 4;
#pragma unroll
    for (int i = 0; i < 4; ++i) {
        const int mbase = m0 + wm + i * 16 + rquad;
#pragma unroll
        for (int j = 0; j < 4; ++j) {
            const int gn = n0 + wn + j * 16 + lrow;
            const float badd = bias[gn];
#pragma unroll
            for (int r = 0; r < 4; ++r)
                C[(size_t)(mbase + r) * D_DIM + gn] = acc[i][j][r] + badd;
        }
    }
}

// ---------------------------------------------------------------- MFMA flash attention
// R8: exact R6 structure (known-good: 69.5us, FETCH 12.3MB, 0 conflicts)
// with ONE delta: softmax in exp2 domain (log2(e) folded into Q pre-scale;
// straight-line, same register structure -- R7's branchy defer-max caused
// scratch spill and is removed). T14 register prefetch of next K/V tile.
// Static (bh,y) grid: XCD = bh%8 L2 affinity; CU-balanced qt map.
// Conflict-free swizzled LDS. l-sum reduction deferred to epilogue.
__global__ __launch_bounds__(256, 4) void attn_mfma_kernel(
        const ushort_t* __restrict__ Q, const ushort_t* __restrict__ K,
        const ushort_t* __restrict__ V, ushort_t* __restrict__ O) {
    __shared__ __align__(16) ushort_t Ks[64 * 64];      // [key][d] swizzled
    __shared__ __align__(16) ushort_t Vt[64 * 64];      // [d][key] swizzled
    __shared__ __align__(16) ushort_t Ps[4][16 * 64];   // per-wave P [row][key] swizzled

    const int bh  = blockIdx.x;
    const int b   = bh >> 4, h = bh & 15;
    const int g   = blockIdx.y & 7;            // CU-balanced qt map
    const int p   = blockIdx.y >> 3;
    const int qt  = (p == 0) ? g : (p == 1) ? (15 - g)
                  : (p == 2) ? (16 + g) : (31 - g);
    const int q0  = qt * 64;
    const int tid = threadIdx.x;
    const int wq  = tid >> 6;
    const int lane = tid & 63;
    const int col  = lane & 15;
    const int quad = lane >> 4;
    const int c7 = col & 7;
    const int qw0  = q0 + wq * 16;             // wave's first q-row
    const size_t rowbase = (size_t)b * S_LEN;
    const int ch0 = h * HD;

    // K staging: thread = (key, 32B d-chunk)
    const int skey = tid >> 2;           // 0..63
    const int schk = tid & 3;            // 0..3
    // V staging: thread = (key-pair, 8-wide d-chunk)
    const int vkp = tid & 31;            // key-pair 0..31
    const int vdc = tid >> 5;            // d-chunk 0..7

    // Q A-fragments: lane holds A[m=col][k=quad*8+e]
    short8 aq[2];
#pragma unroll
    for (int kc = 0; kc < 2; ++kc)
        aq[kc] = *(const short8*)(Q + (rowbase + qw0 + col) * D_DIM
                                    + ch0 + kc * 32 + quad * 8);

    floatx4 oacc[4] = {};
    float mrun[4], lrun[4];
#pragma unroll
    for (int r = 0; r < 4; ++r) { mrun[r] = -1e30f; lrun[r] = 0.0f; }

    const int ntiles = qt + 1;

    // ---- prologue: load tile 0 into registers
    short8 krA, krB, vrA, vrB;
    {
        const ushort_t* kg = K + (rowbase + skey) * D_DIM + ch0 + schk * 16;
        krA = *(const short8*)(kg);
        krB = *(const short8*)(kg + 8);
        const ushort_t* vg = V + (rowbase + 2 * vkp) * D_DIM + ch0 + vdc * 8;
        vrA = *(const short8*)(vg);
        vrB = *(const short8*)(vg + D_DIM);
    }

    for (int t = 0; t < ntiles; ++t) {
        const int kb = t * 64;
        __syncthreads();   // previous tile's LDS reads complete
        // ---- write staged registers to LDS (K swizzled, V transposed pair-packed)
        {
            const int sw = skey & 7;
            *(short8*)(Ks + skey * 64 + (((2 * schk) ^ sw) << 3)) = krA;
            *(short8*)(Ks + skey * 64 + (((2 * schk + 1) ^ sw) << 3)) = krB;
        }
#pragma unroll
        for (int e = 0; e < 8; ++e) {
            const int d = vdc * 8 + e;
            const uint_t pk = (uint_t)(ushort_t)vrA[e] | ((uint_t)(ushort_t)vrB[e] << 16);
            *(uint_t*)(Vt + d * 64 + ((2 * vkp) ^ ((d & 7) << 3))) = pk;
        }
        // ---- prefetch next tile into registers (overlaps with compute below)
        {
            const int kbn = (t + 1 < ntiles) ? (t + 1) * 64 : 0;   // clamp: valid addr
            const ushort_t* kg = K + (rowbase + kbn + skey) * D_DIM + ch0 + schk * 16;
            krA = *(const short8*)(kg);
            krB = *(const short8*)(kg + 8);
            const ushort_t* vg = V + (rowbase + kbn + 2 * vkp) * D_DIM + ch0 + vdc * 8;
            vrA = *(const short8*)(vg);
            vrB = *(const short8*)(vg + D_DIM);
        }
        __syncthreads();   // LDS tile ready

        if (kb <= qw0 + 15) {        // wave-uniform: tile has valid keys
            // ---- S = Q K^T (one ds_read_b128 per fragment, conflict-free)
            floatx4 sa[4] = {};
            __builtin_amdgcn_s_setprio(1);
#pragma unroll
            for (int kc = 0; kc < 2; ++kc)
#pragma unroll
                for (int j = 0; j < 4; ++j) {
                    const short8 bk = *(const short8*)(
                        Ks + (j * 16 + col) * 64 + (((kc * 4 + quad) ^ c7) << 3));
                    sa[j] = __builtin_amdgcn_mfma_f32_16x16x32_bf16(
                        aq[kc], bk, sa[j], 0, 0, 0);
                }
            __builtin_amdgcn_s_setprio(0);

            const bool needmask = (kb + 63 > qw0);
            // ---- causal mask (scale pre-folded into Q)
            if (needmask) {
#pragma unroll
                for (int j = 0; j < 4; ++j)
#pragma unroll
                    for (int r = 0; r < 4; ++r) {
                        const int row = qw0 + quad * 4 + r;
                        const int key = kb + j * 16 + col;
                        if (key > row) sa[j][r] = -1e30f;
                    }
            }
            // ---- online softmax per row, exp2 domain (straight-line)
#pragma unroll
            for (int r = 0; r < 4; ++r) {
                float mx = fmaxf(fmaxf(sa[0][r], sa[1][r]),
                                 fmaxf(sa[2][r], sa[3][r]));
                mx = fmaxf(mx, __shfl_xor(mx, 1));
                mx = fmaxf(mx, __shfl_xor(mx, 2));
                mx = fmaxf(mx, __shfl_xor(mx, 4));
                mx = fmaxf(mx, __shfl_xor(mx, 8));
                const float mn = fmaxf(mrun[r], mx);
                const float al = __builtin_amdgcn_exp2f(mrun[r] - mn);
                mrun[r] = mn;
                float rs = 0.0f;
#pragma unroll
                for (int j = 0; j < 4; ++j) {
                    const float p2 = __builtin_amdgcn_exp2f(sa[j][r] - mn);
                    sa[j][r] = p2;
                    rs += p2;
                }
                lrun[r] = lrun[r] * al + rs;
#pragma unroll
                for (int jd = 0; jd < 4; ++jd) oacc[jd][r] *= al;
            }
            // ---- write P (bf16) to this wave's swizzled LDS region
            {
                ushort_t* pw = Ps[wq];
#pragma unroll
                for (int j = 0; j < 4; ++j)
#pragma unroll
                    for (int r = 0; r < 4; ++r) {
                        const int row = quad * 4 + r;
                        pw[row * 64 + ((j * 16 + col) ^ ((row & 7) << 3))] =
                            f2bf(sa[j][r]);
                    }
            }
            asm volatile("s_waitcnt lgkmcnt(0)" ::: "memory");   // wave-local RAW
            // ---- O += P V
            __builtin_amdgcn_s_setprio(1);
#pragma unroll
            for (int kc = 0; kc < 2; ++kc) {
                const short8 ap = *(const short8*)(
                    Ps[wq] + col * 64 + (((kc * 4 + quad) ^ c7) << 3));
#pragma unroll
                for (int jd = 0; jd < 4; ++jd) {
                    const short8 bv = *(const short8*)(
                        Vt + (jd * 16 + col) * 64 + (((kc * 4 + quad) ^ c7) << 3));
                    oacc[jd] = __builtin_amdgcn_mfma_f32_16x16x32_bf16(
                        ap, bv, oacc[jd], 0, 0, 0);
                }
            }
            __builtin_amdgcn_s_setprio(0);
        }
    }

    // ---- epilogue: reduce l across the 16 key-lanes, write O bf16
#pragma unroll
    for (int r = 0; r < 4; ++r) {
        float l = lrun[r];
        l += __shfl_xor(l, 1);
        l += __shfl_xor(l, 2);
        l += __shfl_xor(l, 4);
        l += __shfl_xor(l, 8);
        const int row = qw0 + quad * 4 + r;
        const float inv = 1.0f / l;
#pragma unroll
        for (int jd = 0; jd < 4; ++jd)
            O[(rowbase + row) * D_DIM + ch0 + jd * 16 + col] =
                f2bf(oacc[jd][r] * inv);
    }
}

// ---------------------------------------------------------------- launch
extern "C" void kernel_launch(void* const* d_in, const int* in_sizes, int n_in,
                              void* d_out, int out_size, void* d_ws, size_t ws_size,
                              hipStream_t stream) {
    const float* x  = (const float*)d_in[0];
    const float* Wq = (const float*)d_in[1];
    const float* Wk = (const float*)d_in[2];
    const float* Wv = (const float*)d_in[3];
    const float* Wo = (const float*)d_in[4];
    const float* bo = (const float*)d_in[5];
    float* out = (float*)d_out;                // f32 output

    char* ws = (char*)d_ws;
    const size_t MB = 1024 * 1024;
    ushort_t* xb  = (ushort_t*)(ws + 0 * MB);   // 8 MB
    ushort_t* WqT = (ushort_t*)(ws + 8 * MB);   // 2 MB each
    ushort_t* WkT = (ushort_t*)(ws + 10 * MB);
    ushort_t* WvT = (ushort_t*)(ws + 12 * MB);
    ushort_t* WoT = (ushort_t*)(ws + 14 * MB);
    ushort_t* Qb  = (ushort_t*)(ws + 16 * MB);  // [B*S, D] bf16, 8 MB each
    ushort_t* Kb  = (ushort_t*)(ws + 24 * MB);
    ushort_t* Vb  = (ushort_t*)(ws + 32 * MB);
    ushort_t* Ob  = (ushort_t*)(ws + 40 * MB);  // total 48 MB

    cast_x_kernel<<<4096, 256, 0, stream>>>(x, xb);
    transpose4_kernel<<<dim3(16, 16, 4), 256, 0, stream>>>(
        Wq, Wk, Wv, Wo, WqT, WkT, WvT, WoT);

    gemm_qkv_kernel<<<dim3(8, 32, 3), 256, 0, stream>>>(
        xb, WqT, WkT, WvT, Qb, Kb, Vb);

    attn_mfma_kernel<<<dim3(32, 32), 256, 0, stream>>>(Qb, Kb, Vb, Ob);

    gemm_out_kernel<<<dim3(8, 32), 256, 0, stream>>>(Ob, WoT, bo, out);
}